// Round 1
// baseline (113.166 us; speedup 1.0000x reference)
//
#include <hip/hip_runtime.h>
#include <math.h>

// RationalQuadraticSpline: B=65536, V=64, K=30 bins.
// Kernel 1: per-variable parameter tables -> d_ws (64 rows x 153 floats).
// Kernel 2: per-element bin search + rational-quadratic spline eval.
//
// Row layout (153 floats, odd stride -> 2-way-max LDS bank aliasing):
//   [0..31]   bounds: cumwidths with bounds[30]=1+EPS, bounds[31]=+big sentinel
//   [32..61]  winv:   1/width per bin
//   [62..91]  cumh:   cumheights[0..29] (bin <= 29 only ever read)
//   [92..121] h:      heights per bin
//   [122..152] der:   derivatives[0..30]

#define NB 65536
#define NV 64
#define NKB 30
#define ROWF 153
#define OFF_B 0
#define OFF_W 32
#define OFF_C 62
#define OFF_H 92
#define OFF_D 122

__global__ void rqs_params(const float* __restrict__ uw,
                           const float* __restrict__ uh,
                           const float* __restrict__ ud,
                           float* __restrict__ P) {
  int v = threadIdx.x;
  if (v >= NV) return;
  float* p = P + v * ROWF;
  const float MINB = 1e-3f;
  const float scale = 1.0f - MINB * (float)NKB;

  // widths -> bounds + winv
  {
    const float* u = uw + v * NKB;
    float m = -1e30f;
    for (int k = 0; k < NKB; ++k) m = fmaxf(m, u[k]);
    float s = 0.f;
    for (int k = 0; k < NKB; ++k) s += expf(u[k] - m);
    float inv = 1.0f / s;
    float c = 0.f, prev = 0.f;
    p[OFF_B + 0] = 0.0f;
    for (int k = 0; k < NKB; ++k) {
      float pk = MINB + scale * (expf(u[k] - m) * inv);
      c += pk;
      float nxt = (k == NKB - 1) ? 1.0f : c;  // cp[-1] forced to hi
      p[OFF_W + k] = 1.0f / (nxt - prev);
      p[OFF_B + k + 1] = nxt;
      prev = nxt;
    }
    p[OFF_B + NKB] = 1.0f + 1e-6f;   // bounds[30] = hi + EPS (search only)
    p[OFF_B + NKB + 1] = 3.0e38f;    // sentinel for binary search
  }
  // heights -> cumh + h
  {
    const float* u = uh + v * NKB;
    float m = -1e30f;
    for (int k = 0; k < NKB; ++k) m = fmaxf(m, u[k]);
    float s = 0.f;
    for (int k = 0; k < NKB; ++k) s += expf(u[k] - m);
    float inv = 1.0f / s;
    float c = 0.f, prev = 0.f;
    for (int k = 0; k < NKB; ++k) {
      float pk = MINB + scale * (expf(u[k] - m) * inv);
      c += pk;
      float nxt = (k == NKB - 1) ? 1.0f : c;
      p[OFF_C + k] = prev;        // cumh[k]
      p[OFF_H + k] = nxt - prev;  // heights[k]
      prev = nxt;
    }
  }
  // derivatives: pad with CONST so softplus(CONST)+MIN_D == 1
  {
    const float CST = (float)log(exp(1.0 - 1e-3) - 1.0);
    for (int k = 0; k <= NKB; ++k) {
      float x = (k == 0 || k == NKB) ? CST : ud[v * (NKB - 1) + (k - 1)];
      float sp = (x > 0.f) ? (x + log1pf(expf(-x))) : log1pf(expf(x));
      p[OFF_D + k] = 1e-3f + sp;
    }
  }
}

__global__ __launch_bounds__(256) void rqs_main(const float* __restrict__ x,
                                                const float* __restrict__ P,
                                                float* __restrict__ out) {
  __shared__ float lds[NV * ROWF];  // 39168 B -> 4 blocks/CU
  // cooperative param copy, float4 (64*153 = 9792 floats = 2448 float4)
  {
    const float4* src = (const float4*)P;
    float4* dst = (float4*)lds;
    for (int i = threadIdx.x; i < (NV * ROWF) / 4; i += 256) dst[i] = src[i];
  }
  __syncthreads();

  const int N = NB * NV;
  int gid = blockIdx.x * 256 + threadIdx.x;
  float4 xv = ((const float4*)x)[gid];
  int v0 = (gid & 15) * 4;  // element (gid*4) % 64; +j stays < 64

  float xs[4] = {xv.x, xv.y, xv.z, xv.w};
  float o[4], l[4];
#pragma unroll
  for (int j = 0; j < 4; ++j) {
    float xx = xs[j];
    const float* row = lds + (v0 + j) * ROWF;
    // binary search: largest k in [0,30] with xx >= bounds[k]
    int idx = 0;
#pragma unroll
    for (int s = 16; s >= 1; s >>= 1) {
      int c = idx + s;
      idx = (xx >= row[OFF_B + c]) ? c : idx;
    }
    int b = idx > 29 ? 29 : idx;

    float icw  = row[OFF_B + b];
    float winv = row[OFF_W + b];
    float ich  = row[OFF_C + b];
    float ih   = row[OFF_H + b];
    float d0   = row[OFF_D + b];
    float d1   = row[OFF_D + b + 1];
    float idl  = ih * winv;  // delta = h/w

    float th   = (xx - icw) * winv;
    float omt  = 1.0f - th;
    float t1mt = th * omt;
    float th2  = th * th;
    float num  = ih * (idl * th2 + d0 * t1mt);
    float den  = idl + (d0 + d1 - 2.0f * idl) * t1mt;
    float so   = ich + __fdividef(num, den);
    float dn   = idl * idl * (d1 * th2 + 2.0f * idl * t1mt + d0 * omt * omt);
    float sl   = __logf(dn) - 2.0f * __logf(den);

    bool inside = !(xx < 0.0f) && !(xx > 1.0f);
    o[j] = inside ? so : xx;   // DERIV_OUT = 1 -> identity outside
    l[j] = inside ? sl : 0.0f;
  }
  float4 ov = {o[0], o[1], o[2], o[3]};
  float4 lv = {l[0], l[1], l[2], l[3]};
  ((float4*)out)[gid] = ov;
  ((float4*)(out + N))[gid] = lv;
}

extern "C" void kernel_launch(void* const* d_in, const int* in_sizes, int n_in,
                              void* d_out, int out_size, void* d_ws, size_t ws_size,
                              hipStream_t stream) {
  const float* x  = (const float*)d_in[0];
  const float* uw = (const float*)d_in[1];
  const float* uh = (const float*)d_in[2];
  const float* ud = (const float*)d_in[3];
  float* out = (float*)d_out;
  float* P   = (float*)d_ws;  // 64*153*4 = 39168 B

  rqs_params<<<1, 64, 0, stream>>>(uw, uh, ud, P);
  rqs_main<<<(NB * NV) / 1024, 256, 0, stream>>>(x, P, out);
}

// Round 3
// 94.650 us; speedup vs baseline: 1.1956x; 1.1956x over previous
//
#include <hip/hip_runtime.h>
#include <math.h>

// RationalQuadraticSpline: B=65536, V=64, K=30 bins.
// Kernel 1 (wave-parallel): one 64-lane block per variable. ALL cross-lane
//   shuffles run with the full wave active (max/sum butterflies + inclusive
//   scan); exclusive prefix derived arithmetically (ci - pk), NOT via a
//   shuffle inside a divergent branch (that was R2's corruption).
// Kernel 2: identical to the round-1 known-good reader (ROWF=153).
//
// Row layout (153 floats, odd stride):
//   [0..31]   bounds: cumwidths, bounds[30]=1+EPS, bounds[31]=sentinel
//   [32..61]  winv:   1/width per bin
//   [62..91]  cumh:   cumheights[0..29]
//   [92..121] h:      heights per bin
//   [122..152] der:   derivatives[0..30]

#define NB 65536
#define NV 64
#define NKB 30
#define ROWF 153
#define OFF_B 0
#define OFF_W 32
#define OFF_C 62
#define OFF_H 92
#define OFF_D 122

__global__ __launch_bounds__(64) void rqs_params(const float* __restrict__ uw,
                                                 const float* __restrict__ uh,
                                                 const float* __restrict__ ud,
                                                 float* __restrict__ P) {
  const int v = blockIdx.x;
  const int lane = threadIdx.x;
  float* p = P + v * ROWF;
  const float MINB = 1e-3f;
  const float scale = 1.0f - MINB * (float)NKB;

  // ---- widths: softmax + floor + prefix scan (all shuffles full-wave) ----
  {
    float u = (lane < NKB) ? uw[v * NKB + lane] : -1e30f;
    float m = u;
#pragma unroll
    for (int s = 32; s >= 1; s >>= 1) m = fmaxf(m, __shfl_xor(m, s));
    float e = (lane < NKB) ? expf(u - m) : 0.0f;
    float t = e;
#pragma unroll
    for (int s = 32; s >= 1; s >>= 1) t += __shfl_xor(t, s);
    float pk = (lane < NKB) ? (MINB + scale * (e / t)) : 0.0f;
    float ci = pk;  // inclusive Hillis-Steele scan, full wave active
#pragma unroll
    for (int s = 1; s < 64; s <<= 1) {
      float z = __shfl_up(ci, s);
      if (lane >= s) ci += z;
    }
    float ce = ci - pk;  // exclusive prefix (lane 0 -> exactly 0)
    float nxt = (lane == NKB - 1) ? 1.0f : ci;  // cp[-1] forced to hi
    if (lane < NKB) {
      p[OFF_B + lane + 1] = nxt;
      p[OFF_W + lane] = 1.0f / (nxt - ce);
    }
    if (lane == 0) p[OFF_B + 0] = 0.0f;
    if (lane == NKB) p[OFF_B + NKB] = 1.0f + 1e-6f;   // hi + EPS (search only)
    if (lane == NKB + 1) p[OFF_B + NKB + 1] = 3.0e38f;  // search sentinel
  }
  // ---- heights ----
  {
    float u = (lane < NKB) ? uh[v * NKB + lane] : -1e30f;
    float m = u;
#pragma unroll
    for (int s = 32; s >= 1; s >>= 1) m = fmaxf(m, __shfl_xor(m, s));
    float e = (lane < NKB) ? expf(u - m) : 0.0f;
    float t = e;
#pragma unroll
    for (int s = 32; s >= 1; s >>= 1) t += __shfl_xor(t, s);
    float pk = (lane < NKB) ? (MINB + scale * (e / t)) : 0.0f;
    float ci = pk;
#pragma unroll
    for (int s = 1; s < 64; s <<= 1) {
      float z = __shfl_up(ci, s);
      if (lane >= s) ci += z;
    }
    float ce = ci - pk;
    float nxt = (lane == NKB - 1) ? 1.0f : ci;
    if (lane < NKB) {
      p[OFF_C + lane] = ce;        // cumh[b]
      p[OFF_H + lane] = nxt - ce;  // height[b]
    }
  }
  // ---- derivatives: pad with CONST so softplus(CONST)+MIN_D == 1 ----
  {
    const float CST = (float)log(exp(1.0 - 1e-3) - 1.0);
    if (lane <= NKB) {
      float x = (lane == 0 || lane == NKB) ? CST : ud[v * (NKB - 1) + lane - 1];
      float sp = (x > 0.f) ? (x + log1pf(expf(-x))) : log1pf(expf(x));
      p[OFF_D + lane] = 1e-3f + sp;
    }
  }
}

__global__ __launch_bounds__(256) void rqs_main(const float* __restrict__ x,
                                                const float* __restrict__ P,
                                                float* __restrict__ out) {
  __shared__ float lds[NV * ROWF];  // 39168 B -> 4 blocks/CU
  {
    const float4* src = (const float4*)P;
    float4* dst = (float4*)lds;
    for (int i = threadIdx.x; i < (NV * ROWF) / 4; i += 256) dst[i] = src[i];
  }
  __syncthreads();

  const int N = NB * NV;
  int gid = blockIdx.x * 256 + threadIdx.x;
  float4 xv = ((const float4*)x)[gid];
  int v0 = (gid & 15) * 4;  // element (gid*4) % 64; +j stays < 64

  float xs[4] = {xv.x, xv.y, xv.z, xv.w};
  float o[4], l[4];
#pragma unroll
  for (int j = 0; j < 4; ++j) {
    float xx = xs[j];
    const float* row = lds + (v0 + j) * ROWF;
    // binary search: largest k in [0,30] with xx >= bounds[k]
    int idx = 0;
#pragma unroll
    for (int s = 16; s >= 1; s >>= 1) {
      int c = idx + s;
      idx = (xx >= row[OFF_B + c]) ? c : idx;
    }
    int b = idx > 29 ? 29 : idx;

    float icw  = row[OFF_B + b];
    float winv = row[OFF_W + b];
    float ich  = row[OFF_C + b];
    float ih   = row[OFF_H + b];
    float d0   = row[OFF_D + b];
    float d1   = row[OFF_D + b + 1];
    float idl  = ih * winv;  // delta = h/w

    float th   = (xx - icw) * winv;
    float omt  = 1.0f - th;
    float t1mt = th * omt;
    float th2  = th * th;
    float num  = ih * (idl * th2 + d0 * t1mt);
    float den  = idl + (d0 + d1 - 2.0f * idl) * t1mt;
    float so   = ich + __fdividef(num, den);
    float dn   = idl * idl * (d1 * th2 + 2.0f * idl * t1mt + d0 * omt * omt);
    float sl   = __logf(dn) - 2.0f * __logf(den);

    bool inside = !(xx < 0.0f) && !(xx > 1.0f);
    o[j] = inside ? so : xx;   // DERIV_OUT = 1 -> identity outside
    l[j] = inside ? sl : 0.0f;
  }
  float4 ov = {o[0], o[1], o[2], o[3]};
  float4 lv = {l[0], l[1], l[2], l[3]};
  ((float4*)out)[gid] = ov;
  ((float4*)(out + N))[gid] = lv;
}

extern "C" void kernel_launch(void* const* d_in, const int* in_sizes, int n_in,
                              void* d_out, int out_size, void* d_ws, size_t ws_size,
                              hipStream_t stream) {
  const float* x  = (const float*)d_in[0];
  const float* uw = (const float*)d_in[1];
  const float* uh = (const float*)d_in[2];
  const float* ud = (const float*)d_in[3];
  float* out = (float*)d_out;
  float* P   = (float*)d_ws;  // 64*153*4 = 39168 B

  rqs_params<<<NV, 64, 0, stream>>>(uw, uh, ud, P);
  rqs_main<<<(NB * NV) / 1024, 256, 0, stream>>>(x, P, out);
}

// Round 4
// 92.010 us; speedup vs baseline: 1.2299x; 1.0287x over previous
//
#include <hip/hip_runtime.h>
#include <math.h>

// RationalQuadraticSpline: B=65536, V=64, K=30 bins.
// Kernel 1 (wave-parallel): one 64-lane block per variable; all cross-lane
//   shuffles full-wave; exclusive prefix = ci - pk (no shuffle-under-divergence).
// Kernel 2 (persistent): 1024 blocks (4/CU), params staged to LDS ONCE per
//   block, grid-stride x4 over elements. Single-log epilogue via rcp(den).
//
// Row layout (153 floats, odd stride):
//   [0..31]   bounds: cumwidths, bounds[30]=1+EPS, bounds[31]=sentinel
//   [32..61]  winv:   1/width per bin        (merges with bounds: ds_read2)
//   [62..91]  cumh:   cumheights[0..29]
//   [92..121] h:      heights per bin        (merges with cumh: ds_read2)
//   [122..152] der:   derivatives[0..30]     (d0,d1 adjacent: ds_read2)

#define NB 65536
#define NV 64
#define NKB 30
#define ROWF 153
#define OFF_B 0
#define OFF_W 32
#define OFF_C 62
#define OFF_H 92
#define OFF_D 122
#define NBLK 1024

__global__ __launch_bounds__(64) void rqs_params(const float* __restrict__ uw,
                                                 const float* __restrict__ uh,
                                                 const float* __restrict__ ud,
                                                 float* __restrict__ P) {
  const int v = blockIdx.x;
  const int lane = threadIdx.x;
  float* p = P + v * ROWF;
  const float MINB = 1e-3f;
  const float scale = 1.0f - MINB * (float)NKB;

  // ---- widths: softmax + floor + prefix scan (all shuffles full-wave) ----
  {
    float u = (lane < NKB) ? uw[v * NKB + lane] : -1e30f;
    float m = u;
#pragma unroll
    for (int s = 32; s >= 1; s >>= 1) m = fmaxf(m, __shfl_xor(m, s));
    float e = (lane < NKB) ? expf(u - m) : 0.0f;
    float t = e;
#pragma unroll
    for (int s = 32; s >= 1; s >>= 1) t += __shfl_xor(t, s);
    float pk = (lane < NKB) ? (MINB + scale * (e / t)) : 0.0f;
    float ci = pk;  // inclusive Hillis-Steele scan, full wave active
#pragma unroll
    for (int s = 1; s < 64; s <<= 1) {
      float z = __shfl_up(ci, s);
      if (lane >= s) ci += z;
    }
    float ce = ci - pk;  // exclusive prefix (lane 0 -> exactly 0)
    float nxt = (lane == NKB - 1) ? 1.0f : ci;  // cp[-1] forced to hi
    if (lane < NKB) {
      p[OFF_B + lane + 1] = nxt;
      p[OFF_W + lane] = 1.0f / (nxt - ce);
    }
    if (lane == 0) p[OFF_B + 0] = 0.0f;
    if (lane == NKB) p[OFF_B + NKB] = 1.0f + 1e-6f;   // hi + EPS (search only)
    if (lane == NKB + 1) p[OFF_B + NKB + 1] = 3.0e38f;  // search sentinel
  }
  // ---- heights ----
  {
    float u = (lane < NKB) ? uh[v * NKB + lane] : -1e30f;
    float m = u;
#pragma unroll
    for (int s = 32; s >= 1; s >>= 1) m = fmaxf(m, __shfl_xor(m, s));
    float e = (lane < NKB) ? expf(u - m) : 0.0f;
    float t = e;
#pragma unroll
    for (int s = 32; s >= 1; s >>= 1) t += __shfl_xor(t, s);
    float pk = (lane < NKB) ? (MINB + scale * (e / t)) : 0.0f;
    float ci = pk;
#pragma unroll
    for (int s = 1; s < 64; s <<= 1) {
      float z = __shfl_up(ci, s);
      if (lane >= s) ci += z;
    }
    float ce = ci - pk;
    float nxt = (lane == NKB - 1) ? 1.0f : ci;
    if (lane < NKB) {
      p[OFF_C + lane] = ce;        // cumh[b]
      p[OFF_H + lane] = nxt - ce;  // height[b]
    }
  }
  // ---- derivatives: pad with CONST so softplus(CONST)+MIN_D == 1 ----
  {
    const float CST = (float)log(exp(1.0 - 1e-3) - 1.0);
    if (lane <= NKB) {
      float x = (lane == 0 || lane == NKB) ? CST : ud[v * (NKB - 1) + lane - 1];
      float sp = (x > 0.f) ? (x + log1pf(expf(-x))) : log1pf(expf(x));
      p[OFF_D + lane] = 1e-3f + sp;
    }
  }
}

__global__ __launch_bounds__(256, 4) void rqs_main(const float* __restrict__ x,
                                                   const float* __restrict__ P,
                                                   float* __restrict__ out) {
  __shared__ float lds[NV * ROWF];  // 39168 B -> 4 blocks/CU
  {
    const float4* src = (const float4*)P;
    float4* dst = (float4*)lds;
    for (int i = threadIdx.x; i < (NV * ROWF) / 4; i += 256) dst[i] = src[i];
  }
  __syncthreads();

  const int N = NB * NV;
  const int n4 = N / 4;  // 1048576 float4 groups; 1024 blk x 256 thr -> 4 iters
  for (int gid = blockIdx.x * 256 + threadIdx.x; gid < n4; gid += NBLK * 256) {
    float4 xv = ((const float4*)x)[gid];
    int v0 = (gid & 15) * 4;  // element (gid*4) % 64; +j stays < 64

    float xs[4] = {xv.x, xv.y, xv.z, xv.w};
    float o[4], l[4];
#pragma unroll
    for (int j = 0; j < 4; ++j) {
      float xx = xs[j];
      const float* row = lds + (v0 + j) * ROWF;
      // binary search: largest k in [0,30] with xx >= bounds[k]
      int idx = 0;
#pragma unroll
      for (int s = 16; s >= 1; s >>= 1) {
        int c = idx + s;
        idx = (xx >= row[OFF_B + c]) ? c : idx;
      }
      int b = idx > 29 ? 29 : idx;

      float icw  = row[OFF_B + b];
      float winv = row[OFF_W + b];
      float ich  = row[OFF_C + b];
      float ih   = row[OFF_H + b];
      float d0   = row[OFF_D + b];
      float d1   = row[OFF_D + b + 1];
      float idl  = ih * winv;  // delta = h/w

      float th   = (xx - icw) * winv;
      float omt  = 1.0f - th;
      float t1mt = th * omt;
      float th2  = th * th;
      float num  = ih * (idl * th2 + d0 * t1mt);
      float den  = idl + (d0 + d1 - 2.0f * idl) * t1mt;
      float rden = __frcp_rn(den);
      float so   = ich + num * rden;
      float dn   = idl * idl * (d1 * th2 + 2.0f * idl * t1mt + d0 * omt * omt);
      float sl   = __logf(dn * rden * rden);  // log(dn) - 2*log(den)

      bool inside = !(xx < 0.0f) && !(xx > 1.0f);
      o[j] = inside ? so : xx;   // DERIV_OUT = 1 -> identity outside
      l[j] = inside ? sl : 0.0f;
    }
    float4 ov = {o[0], o[1], o[2], o[3]};
    float4 lv = {l[0], l[1], l[2], l[3]};
    ((float4*)out)[gid] = ov;
    ((float4*)(out + N))[gid] = lv;
  }
}

extern "C" void kernel_launch(void* const* d_in, const int* in_sizes, int n_in,
                              void* d_out, int out_size, void* d_ws, size_t ws_size,
                              hipStream_t stream) {
  const float* x  = (const float*)d_in[0];
  const float* uw = (const float*)d_in[1];
  const float* uh = (const float*)d_in[2];
  const float* ud = (const float*)d_in[3];
  float* out = (float*)d_out;
  float* P   = (float*)d_ws;  // 64*153*4 = 39168 B

  rqs_params<<<NV, 64, 0, stream>>>(uw, uh, ud, P);
  rqs_main<<<NBLK, 256, 0, stream>>>(x, P, out);
}